// Round 7
// baseline (3168.889 us; speedup 1.0000x reference)
//
#include <hip/hip_runtime.h>
#include <stdint.h>

#define BATCH 256
#define SEQ   512
#define INDIM 64
#define HID   512

typedef _Float16 f16;
typedef _Float16 f16x2 __attribute__((ext_vector_type(2)));
typedef _Float16 f16x8 __attribute__((ext_vector_type(8)));
typedef float    f32x4 __attribute__((ext_vector_type(4)));

#define XP_BYTES  134217728ULL            // 16 blk * 512 s * 32 tiles * 64 lanes * 8 B
#define WSC_BYTES 524288ULL               // 16 kappa * 32 tiles * 64 lanes * 16 B
#define WS_NEED   (XP_BYTES + WSC_BYTES)

// Row permutation making D-layout -> next-step B-frag conversion lane-local.
__device__ __forceinline__ int row_of8(int wv, int rho, int m) {
    return wv*64 + (rho>>1)*32 + (m>>2)*8 + (rho&1)*4 + (m&3);
}
__device__ __forceinline__ f16x2 pkrtz(float a, float b) {
    return __builtin_bit_cast(f16x2, __builtin_amdgcn_cvt_pkrtz(a, b));
}
union FU { f16x8 v; f16x2 h2[4]; uint32_t u[4]; };
__device__ __forceinline__ f16x8 pack8(float4 a, float4 b) {
    FU r;
    r.h2[0] = pkrtz(a.x, a.y); r.h2[1] = pkrtz(a.z, a.w);
    r.h2[2] = pkrtz(b.x, b.y); r.h2[3] = pkrtz(b.z, b.w);
    return r.v;
}
__device__ __forceinline__ float fast_tanh(float x) {
    float e = __expf(2.0f * x);
    return 1.0f - 2.0f * __builtin_amdgcn_rcpf(e + 1.0f);
}
__device__ __forceinline__ f32x4 mfma16(f16x8 a, f16x8 b, f32x4 c) {
    return __builtin_amdgcn_mfma_f32_16x16x32_f16(a, b, c, 0, 0, 0);
}

// ---- sidecar: ALL 16 kappa of W_hh as f16 A-frags, layout [kappa][tau][lane] ----
__global__ void wconv_kernel(const float* __restrict__ W_hh, f16* __restrict__ wsc)
{
    int id = blockIdx.x * 256 + threadIdx.x;      // 0 .. 32767
    if (id >= 16*32*64) return;
    int l = id & 63, tau = (id >> 6) & 31, kap = id >> 11;
    int wv = tau >> 2, rho = tau & 3, g = l >> 4, c = l & 15;
    const float* p = W_hh + (size_t)row_of8(wv, rho, c) * HID + kap * 32 + g * 8;
    f16x8 v = pack8(((const float4*)p)[0], ((const float4*)p)[1]);
    *(f16x8*)(wsc + (size_t)id * 8) = v;
}

// ---- xp = x @ W_ih^T + b_ih + b_hh, stored f16 in D-frag layout ----
__global__ __launch_bounds__(256)
void xp_gemm_kernel(const float* __restrict__ x, const float* __restrict__ W_ih,
                    const float* __restrict__ b_ih, const float* __restrict__ b_hh,
                    f16* __restrict__ xp)
{
    const int t = threadIdx.x, w = t >> 6, l = t & 63, g = l >> 4, c = l & 15;
    const int bb = blockIdx.x;          // batch block 0..15
    const int sc = blockIdx.y;          // s chunk 0..15 (32 s each)

    f16x8 wf[8][2];
    float bias[8][4];
    #pragma unroll
    for (int j = 0; j < 8; ++j) {
        const int tau = w * 8 + j, wv = tau >> 2, rho = tau & 3;
        const float* pr = W_ih + (size_t)row_of8(wv, rho, c) * INDIM;
        #pragma unroll
        for (int kx = 0; kx < 2; ++kx) {
            const float* p4 = pr + kx * 32 + g * 8;
            wf[j][kx] = pack8(((const float4*)p4)[0], ((const float4*)p4)[1]);
        }
        #pragma unroll
        for (int r = 0; r < 4; ++r) {
            int row = row_of8(wv, rho, 4 * g + r);
            bias[j][r] = b_ih[row] + b_hh[row];
        }
    }

    const float* xb = x + (size_t)(bb * 16 + c) * SEQ * INDIM;
    #pragma unroll 1
    for (int si = 0; si < 32; ++si) {
        const int s = sc * 32 + si;
        const float* xs = xb + (size_t)s * INDIM;
        f16x8 bx[2];
        #pragma unroll
        for (int kx = 0; kx < 2; ++kx) {
            const float* p4 = xs + kx * 32 + g * 8;
            bx[kx] = pack8(((const float4*)p4)[0], ((const float4*)p4)[1]);
        }
        #pragma unroll
        for (int j = 0; j < 8; ++j) {
            f32x4 acc; acc[0] = bias[j][0]; acc[1] = bias[j][1];
            acc[2] = bias[j][2]; acc[3] = bias[j][3];
            acc = mfma16(wf[j][0], bx[0], acc);
            acc = mfma16(wf[j][1], bx[1], acc);
            f16x2 lo = pkrtz(acc[0], acc[1]), hi = pkrtz(acc[2], acc[3]);
            uint2 st;
            st.x = __builtin_bit_cast(uint32_t, lo);
            st.y = __builtin_bit_cast(uint32_t, hi);
            size_t idx = (((size_t)bb * SEQ + s) * 32 + w * 8 + j) * 64 + l;
            *(uint2*)(xp + idx * 4) = st;
        }
    }
}

// ---- persistent recurrent kernel: 16 blocks x 512 thr (8 waves, 2/SIMD) ----
__global__ __launch_bounds__(512, 2)
void rnn_mfma9_kernel(const float* __restrict__ h0, const float* __restrict__ W_hh,
                      const f16* __restrict__ xp, const f16* __restrict__ wsc,
                      float* __restrict__ out)
{
    __shared__ f16x8 s_hbuf[2][16 * 64];   // 32 KB: h frag double buffer
    const int t = threadIdx.x, wv = t >> 6, l = t & 63, g = l >> 4, c = l & 15;
    const int bb = blockIdx.x;

    // W_hh kappa (2wv+j)&15, j=0..7 into registers (A-frag layout)
    f16x8 wreg[8][4];
    #pragma unroll
    for (int j = 0; j < 8; ++j) {
        const int kap = (2 * wv + j) & 15;
        #pragma unroll
        for (int rho = 0; rho < 4; ++rho) {
            const float* p4 = W_hh + (size_t)row_of8(wv, rho, c) * HID + kap * 32 + g * 8;
            wreg[j][rho] = pack8(((const float4*)p4)[0], ((const float4*)p4)[1]);
        }
    }

    // h0: own B-frags kept in regs + written to LDS
    f16x8 ownb[2];
    #pragma unroll
    for (int P = 0; P < 2; ++P) {
        const int kap = 2 * wv + P;
        const float* p4 = h0 + (size_t)(bb * 16 + c) * HID + kap * 32 + g * 8;
        ownb[P] = pack8(((const float4*)p4)[0], ((const float4*)p4)[1]);
        s_hbuf[0][kap * 64 + l] = ownb[P];
    }

    // streamed-kappa integer offsets (f16x8 units), loop-invariant
    const f16x8* __restrict__ wsv = (const f16x8*)wsc;
    int koff[8];
    #pragma unroll
    for (int j = 0; j < 8; ++j) {
        const int kap = (2 * wv + 8 + j) & 15;
        koff[j] = (kap * 32 + wv * 4) * 64 + l;
    }

    // xp running pointer; prefetch step 0
    const f16* xq = xp + ((((size_t)bb * SEQ) * 32 + wv * 4) * 64 + l) * 4;
    uint2 xn[4];
    #pragma unroll
    for (int rho = 0; rho < 4; ++rho) xn[rho] = *(const uint2*)(xq + rho * 256);

#define GLOAD1(BUF, J) { \
        BUF[0] = wsv[koff[J]]; BUF[1] = wsv[koff[J] + 64]; \
        BUF[2] = wsv[koff[J] + 128]; BUF[3] = wsv[koff[J] + 192]; }
#define PH_OWN(P) { f16x8 bf = ownb[P]; \
        acc[0] = mfma16(wreg[P][0], bf, acc[0]); \
        acc[1] = mfma16(wreg[P][1], bf, acc[1]); \
        acc[2] = mfma16(wreg[P][2], bf, acc[2]); \
        acc[3] = mfma16(wreg[P][3], bf, acc[3]); }
#define PH_REG(J) { f16x8 bf = hb[(((2 * wv + (J)) & 15)) * 64 + l]; \
        acc[0] = mfma16(wreg[J][0], bf, acc[0]); \
        acc[1] = mfma16(wreg[J][1], bf, acc[1]); \
        acc[2] = mfma16(wreg[J][2], bf, acc[2]); \
        acc[3] = mfma16(wreg[J][3], bf, acc[3]); }
#define PH_STR(BUF, PHI) { f16x8 bf = hb[(((2 * wv + (PHI)) & 15)) * 64 + l]; \
        acc[0] = mfma16(BUF[0], bf, acc[0]); \
        acc[1] = mfma16(BUF[1], bf, acc[1]); \
        acc[2] = mfma16(BUF[2], bf, acc[2]); \
        acc[3] = mfma16(BUF[3], bf, acc[3]); }

    // prologue: first two streamed kappas in flight before step 0
    f16x8 sb0[4], sb1[4], sb2[4], sb3[4], sb4[4], sb5[4], sb6[4], sb7[4];
    GLOAD1(sb0, 0) GLOAD1(sb1, 1)

    __syncthreads();

    int p = 0;
    #pragma unroll 1
    for (int tt = 0; tt < SEQ; ++tt) {
        // acc init from xp (f16 -> f32)
        f32x4 acc[4];
        #pragma unroll
        for (int rho = 0; rho < 4; ++rho) {
            f16x2 lo = __builtin_bit_cast(f16x2, xn[rho].x);
            f16x2 hi = __builtin_bit_cast(f16x2, xn[rho].y);
            f32x4 a; a[0] = (float)lo[0]; a[1] = (float)lo[1];
            a[2] = (float)hi[0]; a[3] = (float)hi[1];
            acc[rho] = a;
        }
        // xp prefetch for next step (running pointer, clamped advance)
        {
            const f16* xr = (tt + 1 < SEQ) ? xq + 8192 : xq;
            #pragma unroll
            for (int rho = 0; rho < 4; ++rho)
                xn[rho] = *(const uint2*)(xr + rho * 256);
            xq = xr;
        }

        const f16x8* hb = &s_hbuf[p][0];

        __builtin_amdgcn_s_setprio(1);
        PH_OWN(0)      GLOAD1(sb2, 2)
        PH_OWN(1)      GLOAD1(sb3, 3)
        PH_STR(sb0, 8) GLOAD1(sb4, 4)
        PH_REG(2)
        PH_STR(sb1, 9) GLOAD1(sb5, 5)
        PH_REG(3)
        PH_STR(sb2, 10) GLOAD1(sb6, 6)
        PH_REG(4)
        PH_STR(sb3, 11) GLOAD1(sb7, 7)
        PH_REG(5)
        PH_STR(sb4, 12)
        PH_REG(6)
        PH_STR(sb5, 13)
        PH_REG(7)
        PH_STR(sb6, 14)
        PH_STR(sb7, 15)
        __builtin_amdgcn_s_setprio(0);

        // tanh -> pack (lane-local) -> own B-frags + LDS
        f16x8* hw = &s_hbuf[1 - p][0];
        #pragma unroll
        for (int P = 0; P < 2; ++P) {
            float t0 = fast_tanh(acc[2*P][0]),   t1 = fast_tanh(acc[2*P][1]);
            float t2 = fast_tanh(acc[2*P][2]),   t3 = fast_tanh(acc[2*P][3]);
            float t4 = fast_tanh(acc[2*P+1][0]), t5 = fast_tanh(acc[2*P+1][1]);
            float t6 = fast_tanh(acc[2*P+1][2]), t7 = fast_tanh(acc[2*P+1][3]);
            FU fu;
            fu.h2[0] = pkrtz(t0, t1); fu.h2[1] = pkrtz(t2, t3);
            fu.h2[2] = pkrtz(t4, t5); fu.h2[3] = pkrtz(t6, t7);
            ownb[P] = fu.v;
            hw[(2 * wv + P) * 64 + l] = fu.v;
            if (tt == SEQ - 1) {
                float* ob = out + (size_t)(bb * 16 + c) * HID;
                float* o2 = ob + (size_t)BATCH * HID;
                int ra = row_of8(wv, 2 * P, 4 * g);      // rows ra..ra+3 = t0..t3
                int rb = ra + 4;                          // rows rb..rb+3 = t4..t7
                ob[ra + 0] = t0; ob[ra + 1] = t1; ob[ra + 2] = t2; ob[ra + 3] = t3;
                ob[rb + 0] = t4; ob[rb + 1] = t5; ob[rb + 2] = t6; ob[rb + 3] = t7;
                o2[ra + 0] = t0; o2[ra + 1] = t1; o2[ra + 2] = t2; o2[ra + 3] = t3;
                o2[rb + 0] = t4; o2[rb + 1] = t5; o2[rb + 2] = t6; o2[rb + 3] = t7;
            }
        }

        // prefetch next step's first two streamed kappas (stay in flight across barrier)
        GLOAD1(sb0, 0) GLOAD1(sb1, 1)

        // step barrier: drain LDS ops only; global loads stay in flight
        asm volatile("s_waitcnt lgkmcnt(0)" ::: "memory");
        __builtin_amdgcn_s_barrier();
        asm volatile("" ::: "memory");
        p ^= 1;
    }
#undef GLOAD1
#undef PH_OWN
#undef PH_REG
#undef PH_STR
}

// =================== fallback (round-2 kernel, proven 962 us) ===============
typedef _Float16 half2_t __attribute__((ext_vector_type(2)));
__device__ __forceinline__ float dot2f(uint32_t w, uint32_t h, float acc) {
    return __builtin_amdgcn_fdot2(__builtin_bit_cast(half2_t, w),
                                  __builtin_bit_cast(half2_t, h), acc, false);
}
__device__ __forceinline__ uint32_t pack2(float a, float b) {
    half2_t h; h[0] = (_Float16)a; h[1] = (_Float16)b;
    return __builtin_bit_cast(uint32_t, h);
}
template<int CTRL>
__device__ __forceinline__ float dpp_sum(float x) {
    int xi = __builtin_bit_cast(int, x);
    int yi = __builtin_amdgcn_mov_dpp(xi, CTRL, 0xF, 0xF, true);
    return x + __builtin_bit_cast(float, yi);
}
__device__ __forceinline__ float swz4_sum(float x) {
    int xi = __builtin_bit_cast(int, x);
    int yi = __builtin_amdgcn_ds_swizzle(xi, 0x101F);
    return x + __builtin_bit_cast(float, yi);
}
struct SmemFB {
    uint4     wl[16][512];
    _Float16  hbuf[2][8][72];
};
#define FB_DOT4(accv, wrow, hc) \
    accv = dot2f((wrow)[0], hc.x, accv); accv = dot2f((wrow)[1], hc.y, accv); \
    accv = dot2f((wrow)[2], hc.z, accv); accv = dot2f((wrow)[3], hc.w, accv);

__global__ __launch_bounds__(512, 2)
void rnn_ksplit_kernel(const float* __restrict__ x, const float* __restrict__ h0,
                       const float* __restrict__ W_ih, const float* __restrict__ W_hh,
                       const float* __restrict__ b_ih, const float* __restrict__ b_hh,
                       float* __restrict__ out)
{
    __shared__ SmemFB sm;
    const int t = threadIdx.x;
    const int b = blockIdx.x;
    const int s = t & 7;
    const int rbase = t & ~7;

    uint32_t wreg[6][32];
    #pragma unroll
    for (int j = 0; j < 6; ++j) {
        const float* wr = W_hh + (size_t)(rbase + j) * HID + s * 64;
        #pragma unroll
        for (int q = 0; q < 16; ++q) {
            float4 v4 = ((const float4*)wr)[q];
            wreg[j][2*q]   = pack2(v4.x, v4.y);
            wreg[j][2*q+1] = pack2(v4.z, v4.w);
        }
    }
    #pragma unroll
    for (int v = 0; v < 2; ++v) {
        const float* wr = W_hh + (size_t)(rbase + 6 + v) * HID + s * 64;
        #pragma unroll
        for (int cc = 0; cc < 8; ++cc) {
            float4 aa = ((const float4*)wr)[2*cc];
            float4 bb2 = ((const float4*)wr)[2*cc+1];
            uint4 wv2;
            wv2.x = pack2(aa.x, aa.y); wv2.y = pack2(aa.z, aa.w);
            wv2.z = pack2(bb2.x, bb2.y); wv2.w = pack2(bb2.z, bb2.w);
            sm.wl[v*8 + cc][t] = wv2;
        }
    }
    uint32_t wih[8][4];
    #pragma unroll
    for (int j = 0; j < 8; ++j) {
        const float* wr = W_ih + (size_t)(rbase + j) * INDIM + s * 8;
        float4 aa = ((const float4*)wr)[0];
        float4 bb2 = ((const float4*)wr)[1];
        wih[j][0] = pack2(aa.x, aa.y); wih[j][1] = pack2(aa.z, aa.w);
        wih[j][2] = pack2(bb2.x, bb2.y); wih[j][3] = pack2(bb2.z, bb2.w);
    }
    const float bsum = b_ih[t] + b_hh[t];
    sm.hbuf[0][t >> 6][t & 63] = (_Float16)h0[(size_t)b * HID + t];
    const float* xbase = x + (size_t)b * SEQ * INDIM + s * 8;
    float4 xa = ((const float4*)xbase)[0];
    float4 xb = ((const float4*)xbase)[1];
    const bool b0 = (s & 1) != 0, b1 = (s & 2) != 0, b2 = (s & 4) != 0;
    __syncthreads();

    float hlast = 0.f;
    #pragma unroll 1
    for (int tt = 0; tt < SEQ; ++tt) {
        const int tn = (tt + 1 < SEQ) ? tt + 1 : tt;
        const float* xpf = xbase + (size_t)tn * INDIM;
        float4 xa_n = ((const float4*)xpf)[0];
        float4 xb_n = ((const float4*)xpf)[1];
        const int par = tt & 1;
        float a0=0,a1=0,a2=0,a3=0,a4=0,a5=0,a6=0,a7=0;
        const uint4* hp = (const uint4*)&sm.hbuf[par][s][0];
        #pragma unroll
        for (int cc = 0; cc < 8; ++cc) {
            uint4 hc = hp[cc];
            uint4 w6 = sm.wl[cc][t];
            uint4 w7 = sm.wl[8 + cc][t];
            FB_DOT4(a0, &wreg[0][4*cc], hc);
            FB_DOT4(a1, &wreg[1][4*cc], hc);
            FB_DOT4(a2, &wreg[2][4*cc], hc);
            FB_DOT4(a3, &wreg[3][4*cc], hc);
            FB_DOT4(a4, &wreg[4][4*cc], hc);
            FB_DOT4(a5, &wreg[5][4*cc], hc);
            a6 = dot2f(w6.x, hc.x, a6); a6 = dot2f(w6.y, hc.y, a6);
            a6 = dot2f(w6.z, hc.z, a6); a6 = dot2f(w6.w, hc.w, a6);
            a7 = dot2f(w7.x, hc.x, a7); a7 = dot2f(w7.y, hc.y, a7);
            a7 = dot2f(w7.z, hc.z, a7); a7 = dot2f(w7.w, hc.w, a7);
        }
        {
            uint32_t xp0 = pack2(xa.x, xa.y), xp1 = pack2(xa.z, xa.w);
            uint32_t xp2 = pack2(xb.x, xb.y), xp3 = pack2(xb.z, xb.w);
            uint4 xc; xc.x = xp0; xc.y = xp1; xc.z = xp2; xc.w = xp3;
            FB_DOT4(a0, wih[0], xc); FB_DOT4(a1, wih[1], xc);
            FB_DOT4(a2, wih[2], xc); FB_DOT4(a3, wih[3], xc);
            FB_DOT4(a4, wih[4], xc); FB_DOT4(a5, wih[5], xc);
            FB_DOT4(a6, wih[6], xc); FB_DOT4(a7, wih[7], xc);
        }
        float t0 = dpp_sum<0xB1>(a0), u0 = dpp_sum<0xB1>(a1);
        float t1 = dpp_sum<0xB1>(a2), u1 = dpp_sum<0xB1>(a3);
        float t2 = dpp_sum<0xB1>(a4), u2 = dpp_sum<0xB1>(a5);
        float t3 = dpp_sum<0xB1>(a6), u3 = dpp_sum<0xB1>(a7);
        float q0 = b0 ? u0 : t0;
        float q1 = b0 ? u1 : t1;
        float q2 = b0 ? u2 : t2;
        float q3 = b0 ? u3 : t3;
        float r0a = dpp_sum<0x4E>(q0), r0b = dpp_sum<0x4E>(q1);
        float r1a = dpp_sum<0x4E>(q2), r1b = dpp_sum<0x4E>(q3);
        float r0 = b1 ? r0b : r0a;
        float r1 = b1 ? r1b : r1a;
        float f0 = swz4_sum(r0), f1 = swz4_sum(r1);
        float accv = (b2 ? f1 : f0) + bsum;
        float e  = __expf(2.0f * accv);
        float th = 1.0f - 2.0f * __builtin_amdgcn_rcpf(e + 1.0f);
        sm.hbuf[1 - par][t >> 6][t & 63] = (_Float16)th;
        hlast = th;
        xa = xa_n; xb = xb_n;
        __syncthreads();
    }
    out[(size_t)b * HID + t] = hlast;
    out[(size_t)BATCH * HID + (size_t)b * HID + t] = hlast;
}

extern "C" void kernel_launch(void* const* d_in, const int* in_sizes, int n_in,
                              void* d_out, int out_size, void* d_ws, size_t ws_size,
                              hipStream_t stream) {
    (void)in_sizes; (void)n_in; (void)out_size;
    const float* x    = (const float*)d_in[0];
    const float* h0   = (const float*)d_in[1];
    const float* W_ih = (const float*)d_in[2];
    const float* W_hh = (const float*)d_in[3];
    const float* b_ih = (const float*)d_in[4];
    const float* b_hh = (const float*)d_in[5];
    float* out = (float*)d_out;

    if (ws_size >= WS_NEED) {
        f16* xp  = (f16*)d_ws;
        f16* wsc = (f16*)((char*)d_ws + XP_BYTES);
        hipLaunchKernelGGL(wconv_kernel, dim3(128), dim3(256), 0, stream, W_hh, wsc);
        hipLaunchKernelGGL(xp_gemm_kernel, dim3(16, 16), dim3(256), 0, stream,
                           x, W_ih, b_ih, b_hh, xp);
        hipLaunchKernelGGL(rnn_mfma9_kernel, dim3(16), dim3(512), 0, stream,
                           h0, W_hh, xp, wsc, out);
    } else {
        hipLaunchKernelGGL(rnn_ksplit_kernel, dim3(BATCH), dim3(512), 0, stream,
                           x, h0, W_ih, W_hh, b_ih, b_hh, out);
    }
}

// Round 8
// 2666.188 us; speedup vs baseline: 1.1885x; 1.1885x over previous
//
#include <hip/hip_runtime.h>
#include <stdint.h>

#define BATCH 256
#define SEQ   512
#define INDIM 64
#define HID   512

typedef _Float16 f16;
typedef _Float16 f16x2 __attribute__((ext_vector_type(2)));
typedef _Float16 f16x8 __attribute__((ext_vector_type(8)));
typedef float    f32x4 __attribute__((ext_vector_type(4)));
typedef unsigned long long u64;

#define XP_BYTES   134217728ULL   // 16 bb * 512 s * 32 tau * 64 lanes * 8 B
#define EXCH_BYTES 524288ULL      // 32 blk * 2 slot * 8 frag * 64 lanes * 16 B
#define FLAG_BYTES 2048ULL        // 32 blk * 64 B
#define WS_NEED    (XP_BYTES + EXCH_BYTES + FLAG_BYTES)

// Row permutation: D-layout -> next-step B-frag conversion is lane-local.
// tau in [0,32) indexes 16-row tiles; m in [0,16).
__device__ __forceinline__ int rowmap(int tau, int m) {
    return (tau >> 1) * 32 + (m >> 2) * 8 + (tau & 1) * 4 + (m & 3);
}
__device__ __forceinline__ f16x2 pkrtz(float a, float b) {
    return __builtin_bit_cast(f16x2, __builtin_amdgcn_cvt_pkrtz(a, b));
}
union FU { f16x8 v; f16x2 h2[4]; uint32_t u[4]; u64 q[2]; };
__device__ __forceinline__ f16x8 pack8(float4 a, float4 b) {
    FU r;
    r.h2[0] = pkrtz(a.x, a.y); r.h2[1] = pkrtz(a.z, a.w);
    r.h2[2] = pkrtz(b.x, b.y); r.h2[3] = pkrtz(b.z, b.w);
    return r.v;
}
__device__ __forceinline__ float fast_tanh(float x) {
    float e = __expf(2.0f * x);
    return 1.0f - 2.0f * __builtin_amdgcn_rcpf(e + 1.0f);
}
__device__ __forceinline__ f32x4 mfma16(f16x8 a, f16x8 b, f32x4 c) {
    return __builtin_amdgcn_mfma_f32_16x16x32_f16(a, b, c, 0, 0, 0);
}
__device__ __forceinline__ void st64a(u64* p, u64 v) {
    __hip_atomic_store(p, v, __ATOMIC_RELAXED, __HIP_MEMORY_SCOPE_AGENT);
}
__device__ __forceinline__ u64 ld64a(const u64* p) {
    return __hip_atomic_load(p, __ATOMIC_RELAXED, __HIP_MEMORY_SCOPE_AGENT);
}

// ---- xp = x @ W_ih^T + b_ih + b_hh, stored f16 in D-frag layout ----
__global__ __launch_bounds__(256)
void xp_gemm_kernel(const float* __restrict__ x, const float* __restrict__ W_ih,
                    const float* __restrict__ b_ih, const float* __restrict__ b_hh,
                    f16* __restrict__ xp)
{
    const int t = threadIdx.x, w = t >> 6, l = t & 63, g = l >> 4, c = l & 15;
    const int bb = blockIdx.x;          // batch block 0..15
    const int sc = blockIdx.y;          // s chunk 0..15

    f16x8 wf[8][2];
    float bias[8][4];
    #pragma unroll
    for (int j = 0; j < 8; ++j) {
        const int tau = w * 8 + j;
        const float* pr = W_ih + (size_t)rowmap(tau, c) * INDIM;
        #pragma unroll
        for (int kx = 0; kx < 2; ++kx) {
            const float* p4 = pr + kx * 32 + g * 8;
            wf[j][kx] = pack8(((const float4*)p4)[0], ((const float4*)p4)[1]);
        }
        #pragma unroll
        for (int r = 0; r < 4; ++r) {
            int row = rowmap(tau, 4 * g + r);
            bias[j][r] = b_ih[row] + b_hh[row];
        }
    }

    const float* xb = x + (size_t)(bb * 16 + c) * SEQ * INDIM;
    #pragma unroll 1
    for (int si = 0; si < 32; ++si) {
        const int s = sc * 32 + si;
        const float* xs = xb + (size_t)s * INDIM;
        f16x8 bx[2];
        #pragma unroll
        for (int kx = 0; kx < 2; ++kx) {
            const float* p4 = xs + kx * 32 + g * 8;
            bx[kx] = pack8(((const float4*)p4)[0], ((const float4*)p4)[1]);
        }
        #pragma unroll
        for (int j = 0; j < 8; ++j) {
            f32x4 acc; acc[0] = bias[j][0]; acc[1] = bias[j][1];
            acc[2] = bias[j][2]; acc[3] = bias[j][3];
            acc = mfma16(wf[j][0], bx[0], acc);
            acc = mfma16(wf[j][1], bx[1], acc);
            f16x2 lo = pkrtz(acc[0], acc[1]), hi = pkrtz(acc[2], acc[3]);
            uint2 st;
            st.x = __builtin_bit_cast(uint32_t, lo);
            st.y = __builtin_bit_cast(uint32_t, hi);
            size_t idx = (((size_t)bb * SEQ + s) * 32 + w * 8 + j) * 64 + l;
            *(uint2*)(xp + idx * 4) = st;
        }
    }
}

// ---- pair-split recurrent kernel: 32 blocks (16 pairs), 512 thr, all W in regs ----
__global__ __launch_bounds__(512, 2)
void rnn_pair_kernel(const float* __restrict__ h0, const float* __restrict__ W_hh,
                     const f16* __restrict__ xp, u64* __restrict__ exch64,
                     uint32_t* __restrict__ flags, float* __restrict__ out)
{
    __shared__ f16x8 s_h[2][8 * 64];    // 16 KB: local-half h frags, double-buffered
    const int t = threadIdx.x, w = t >> 6, l = t & 63, g = l >> 4, c = l & 15;
    const int bb   = blockIdx.x >> 1;
    const int half = blockIdx.x & 1;
    const int myblk = bb * 2 + half, pblk = bb * 2 + (1 - half);
    const int LB = half * 8, RB = (1 - half) * 8;   // local / remote kappa bases

    // ---- W_hh: this block's 256 rows, ALL 16 kappa, in registers -------------
    // wregL[j]: cols of local kappa (w+j)&7 + LB ; wregR[j]: remote kappa RB+j.
    f16x8 wregL[8][2], wregR[8][2];
    #pragma unroll
    for (int j = 0; j < 8; ++j) {
        const int klc = (LB + ((w + j) & 7)) * 32 + g * 8;
        const int krc = (RB + j) * 32 + g * 8;
        #pragma unroll
        for (int rho = 0; rho < 2; ++rho) {
            const float* pr = W_hh + (size_t)rowmap(half * 16 + w * 2 + rho, c) * HID;
            wregL[j][rho] = pack8(((const float4*)(pr + klc))[0],
                                  ((const float4*)(pr + klc))[1]);
            wregR[j][rho] = pack8(((const float4*)(pr + krc))[0],
                                  ((const float4*)(pr + krc))[1]);
        }
    }

    // ---- h0 bootstrap: local frag (kappa LB+w) to LDS; remote frags to regs ---
    const float* h0b = h0 + (size_t)(bb * 16 + c) * HID;
    {
        const float* p4 = h0b + (LB + w) * 32 + g * 8;
        s_h[0][w * 64 + l] = pack8(((const float4*)p4)[0], ((const float4*)p4)[1]);
    }
    u64 rq[16];
    #pragma unroll
    for (int j = 0; j < 8; ++j) {
        const float* p4 = h0b + (RB + j) * 32 + g * 8;
        FU u; u.v = pack8(((const float4*)p4)[0], ((const float4*)p4)[1]);
        rq[2 * j] = u.q[0]; rq[2 * j + 1] = u.q[1];
    }

    // xp running pointer (tau0 = half*16 + w*2), prefetch step 0
    const f16* xq = xp + ((((size_t)bb * SEQ) * 32 + half * 16 + w * 2) * 64 + l) * 4;
    uint2 xn0 = *(const uint2*)(xq);
    uint2 xn1 = *(const uint2*)(xq + 256);

    uint32_t* myflag = flags + myblk * 16;
    uint32_t* pflag  = flags + pblk * 16;

#define PH_LOC(J) { const int kl = (w + (J)) & 7; f16x8 bf = hb[kl * 64 + l]; \
        acc0 = mfma16(wregL[J][0], bf, acc0); acc1 = mfma16(wregL[J][1], bf, acc1); }
#define PH_REM(J) { FU u; u.q[0] = rq[2*(J)]; u.q[1] = rq[2*(J)+1]; \
        acc0 = mfma16(wregR[J][0], u.v, acc0); acc1 = mfma16(wregR[J][1], u.v, acc1); }

    __syncthreads();

    int p = 0;
    #pragma unroll 1
    for (int tt = 0; tt < SEQ; ++tt) {
        // acc init from xp
        f32x4 acc0, acc1;
        {
            f16x2 lo = __builtin_bit_cast(f16x2, xn0.x);
            f16x2 hi = __builtin_bit_cast(f16x2, xn0.y);
            acc0[0] = (float)lo[0]; acc0[1] = (float)lo[1];
            acc0[2] = (float)hi[0]; acc0[3] = (float)hi[1];
            lo = __builtin_bit_cast(f16x2, xn1.x);
            hi = __builtin_bit_cast(f16x2, xn1.y);
            acc1[0] = (float)lo[0]; acc1[1] = (float)lo[1];
            acc1[2] = (float)hi[0]; acc1[3] = (float)hi[1];
        }
        // issue next-step xp loads now (drained by tail fence, held across barrier)
        {
            const f16* xr = xq + ((tt + 1 < SEQ) ? 8192 : 0);
            xn0 = *(const uint2*)(xr);
            xn1 = *(const uint2*)(xr + 256);
            xq = xr;
        }

        const f16x8* hb = &s_h[p][0];
        PH_LOC(0) PH_LOC(1) PH_LOC(2) PH_LOC(3)
        PH_LOC(4) PH_LOC(5) PH_LOC(6) PH_LOC(7)
        PH_REM(0) PH_REM(1) PH_REM(2) PH_REM(3)
        PH_REM(4) PH_REM(5) PH_REM(6) PH_REM(7)

        // tanh -> pack: fu = B-frag of kappa LB+w (lane-local by construction)
        float t0 = fast_tanh(acc0[0]), t1 = fast_tanh(acc0[1]);
        float t2 = fast_tanh(acc0[2]), t3 = fast_tanh(acc0[3]);
        float t4 = fast_tanh(acc1[0]), t5 = fast_tanh(acc1[1]);
        float t6 = fast_tanh(acc1[2]), t7 = fast_tanh(acc1[3]);
        FU fu;
        fu.h2[0] = pkrtz(t0, t1); fu.h2[1] = pkrtz(t2, t3);
        fu.h2[2] = pkrtz(t4, t5); fu.h2[3] = pkrtz(t6, t7);

        if (tt == SEQ - 1) {
            float* ob = out + (size_t)(bb * 16 + c) * HID;
            float* o2 = ob + (size_t)BATCH * HID;
            const int ra = half * 256 + w * 32 + g * 8;
            ob[ra + 0] = t0; ob[ra + 1] = t1; ob[ra + 2] = t2; ob[ra + 3] = t3;
            ob[ra + 4] = t4; ob[ra + 5] = t5; ob[ra + 6] = t6; ob[ra + 7] = t7;
            o2[ra + 0] = t0; o2[ra + 1] = t1; o2[ra + 2] = t2; o2[ra + 3] = t3;
            o2[ra + 4] = t4; o2[ra + 5] = t5; o2[ra + 6] = t6; o2[ra + 7] = t7;
            break;
        }

        const int slot = (tt + 1) & 1;
        // publish: LDS (local waves) + exchange (partner, sc1 -> L3)
        s_h[1 - p][w * 64 + l] = fu.v;
        {
            u64* pw = exch64 + (((size_t)myblk * 2 + slot) * 512 + w * 64 + l) * 2;
            st64a(pw, fu.q[0]); st64a(pw + 1, fu.q[1]);
        }

        // drain my stores (exchange to L3, LDS visible), then block barrier
        asm volatile("s_waitcnt vmcnt(0) lgkmcnt(0)" ::: "memory");
        __builtin_amdgcn_s_barrier();

        if (t == 0)
            __hip_atomic_store(myflag, (uint32_t)(tt + 1),
                               __ATOMIC_RELEASE, __HIP_MEMORY_SCOPE_AGENT);

        // acquire partner's step tt+1 data; load remote frags for next step
        {
            const uint32_t want = tt + 1;
            uint32_t guard = 0;
            while (__hip_atomic_load(pflag, __ATOMIC_ACQUIRE,
                                     __HIP_MEMORY_SCOPE_AGENT) < want) {
                if (++guard > (1u << 20)) break;
                __builtin_amdgcn_s_sleep(2);
            }
            const u64* pr = exch64 + (((size_t)pblk * 2 + slot) * 512 + l) * 2;
            rq[0]  = ld64a(pr + 0 * 128); rq[1]  = ld64a(pr + 0 * 128 + 1);
            rq[2]  = ld64a(pr + 1 * 128); rq[3]  = ld64a(pr + 1 * 128 + 1);
            rq[4]  = ld64a(pr + 2 * 128); rq[5]  = ld64a(pr + 2 * 128 + 1);
            rq[6]  = ld64a(pr + 3 * 128); rq[7]  = ld64a(pr + 3 * 128 + 1);
            rq[8]  = ld64a(pr + 4 * 128); rq[9]  = ld64a(pr + 4 * 128 + 1);
            rq[10] = ld64a(pr + 5 * 128); rq[11] = ld64a(pr + 5 * 128 + 1);
            rq[12] = ld64a(pr + 6 * 128); rq[13] = ld64a(pr + 6 * 128 + 1);
            rq[14] = ld64a(pr + 7 * 128); rq[15] = ld64a(pr + 7 * 128 + 1);
        }
        p ^= 1;
    }
#undef PH_LOC
#undef PH_REM
}

// =================== fallback (round-2 kernel, proven 962 us) ===============
typedef _Float16 half2_t __attribute__((ext_vector_type(2)));
__device__ __forceinline__ float dot2f(uint32_t w, uint32_t h, float acc) {
    return __builtin_amdgcn_fdot2(__builtin_bit_cast(half2_t, w),
                                  __builtin_bit_cast(half2_t, h), acc, false);
}
__device__ __forceinline__ uint32_t pack2(float a, float b) {
    half2_t h; h[0] = (_Float16)a; h[1] = (_Float16)b;
    return __builtin_bit_cast(uint32_t, h);
}
template<int CTRL>
__device__ __forceinline__ float dpp_sum(float x) {
    int xi = __builtin_bit_cast(int, x);
    int yi = __builtin_amdgcn_mov_dpp(xi, CTRL, 0xF, 0xF, true);
    return x + __builtin_bit_cast(float, yi);
}
__device__ __forceinline__ float swz4_sum(float x) {
    int xi = __builtin_bit_cast(int, x);
    int yi = __builtin_amdgcn_ds_swizzle(xi, 0x101F);
    return x + __builtin_bit_cast(float, yi);
}
struct SmemFB {
    uint4     wl[16][512];
    _Float16  hbuf[2][8][72];
};
#define FB_DOT4(accv, wrow, hc) \
    accv = dot2f((wrow)[0], hc.x, accv); accv = dot2f((wrow)[1], hc.y, accv); \
    accv = dot2f((wrow)[2], hc.z, accv); accv = dot2f((wrow)[3], hc.w, accv);

__global__ __launch_bounds__(512, 2)
void rnn_ksplit_kernel(const float* __restrict__ x, const float* __restrict__ h0,
                       const float* __restrict__ W_ih, const float* __restrict__ W_hh,
                       const float* __restrict__ b_ih, const float* __restrict__ b_hh,
                       float* __restrict__ out)
{
    __shared__ SmemFB sm;
    const int t = threadIdx.x;
    const int b = blockIdx.x;
    const int s = t & 7;
    const int rbase = t & ~7;

    uint32_t wreg[6][32];
    #pragma unroll
    for (int j = 0; j < 6; ++j) {
        const float* wr = W_hh + (size_t)(rbase + j) * HID + s * 64;
        #pragma unroll
        for (int q = 0; q < 16; ++q) {
            float4 v4 = ((const float4*)wr)[q];
            wreg[j][2*q]   = pack2(v4.x, v4.y);
            wreg[j][2*q+1] = pack2(v4.z, v4.w);
        }
    }
    #pragma unroll
    for (int v = 0; v < 2; ++v) {
        const float* wr = W_hh + (size_t)(rbase + 6 + v) * HID + s * 64;
        #pragma unroll
        for (int cc = 0; cc < 8; ++cc) {
            float4 aa = ((const float4*)wr)[2*cc];
            float4 bb2 = ((const float4*)wr)[2*cc+1];
            uint4 wv2;
            wv2.x = pack2(aa.x, aa.y); wv2.y = pack2(aa.z, aa.w);
            wv2.z = pack2(bb2.x, bb2.y); wv2.w = pack2(bb2.z, bb2.w);
            sm.wl[v*8 + cc][t] = wv2;
        }
    }
    uint32_t wih[8][4];
    #pragma unroll
    for (int j = 0; j < 8; ++j) {
        const float* wr = W_ih + (size_t)(rbase + j) * INDIM + s * 8;
        float4 aa = ((const float4*)wr)[0];
        float4 bb2 = ((const float4*)wr)[1];
        wih[j][0] = pack2(aa.x, aa.y); wih[j][1] = pack2(aa.z, aa.w);
        wih[j][2] = pack2(bb2.x, bb2.y); wih[j][3] = pack2(bb2.z, bb2.w);
    }
    const float bsum = b_ih[t] + b_hh[t];
    sm.hbuf[0][t >> 6][t & 63] = (_Float16)h0[(size_t)b * HID + t];
    const float* xbase = x + (size_t)b * SEQ * INDIM + s * 8;
    float4 xa = ((const float4*)xbase)[0];
    float4 xb = ((const float4*)xbase)[1];
    const bool b0 = (s & 1) != 0, b1 = (s & 2) != 0, b2 = (s & 4) != 0;
    __syncthreads();

    float hlast = 0.f;
    #pragma unroll 1
    for (int tt = 0; tt < SEQ; ++tt) {
        const int tn = (tt + 1 < SEQ) ? tt + 1 : tt;
        const float* xpf = xbase + (size_t)tn * INDIM;
        float4 xa_n = ((const float4*)xpf)[0];
        float4 xb_n = ((const float4*)xpf)[1];
        const int par = tt & 1;
        float a0=0,a1=0,a2=0,a3=0,a4=0,a5=0,a6=0,a7=0;
        const uint4* hp = (const uint4*)&sm.hbuf[par][s][0];
        #pragma unroll
        for (int cc = 0; cc < 8; ++cc) {
            uint4 hc = hp[cc];
            uint4 w6 = sm.wl[cc][t];
            uint4 w7 = sm.wl[8 + cc][t];
            FB_DOT4(a0, &wreg[0][4*cc], hc);
            FB_DOT4(a1, &wreg[1][4*cc], hc);
            FB_DOT4(a2, &wreg[2][4*cc], hc);
            FB_DOT4(a3, &wreg[3][4*cc], hc);
            FB_DOT4(a4, &wreg[4][4*cc], hc);
            FB_DOT4(a5, &wreg[5][4*cc], hc);
            a6 = dot2f(w6.x, hc.x, a6); a6 = dot2f(w6.y, hc.y, a6);
            a6 = dot2f(w6.z, hc.z, a6); a6 = dot2f(w6.w, hc.w, a6);
            a7 = dot2f(w7.x, hc.x, a7); a7 = dot2f(w7.y, hc.y, a7);
            a7 = dot2f(w7.z, hc.z, a7); a7 = dot2f(w7.w, hc.w, a7);
        }
        {
            uint32_t xp0 = pack2(xa.x, xa.y), xp1 = pack2(xa.z, xa.w);
            uint32_t xp2 = pack2(xb.x, xb.y), xp3 = pack2(xb.z, xb.w);
            uint4 xc; xc.x = xp0; xc.y = xp1; xc.z = xp2; xc.w = xp3;
            FB_DOT4(a0, wih[0], xc); FB_DOT4(a1, wih[1], xc);
            FB_DOT4(a2, wih[2], xc); FB_DOT4(a3, wih[3], xc);
            FB_DOT4(a4, wih[4], xc); FB_DOT4(a5, wih[5], xc);
            FB_DOT4(a6, wih[6], xc); FB_DOT4(a7, wih[7], xc);
        }
        float t0 = dpp_sum<0xB1>(a0), u0 = dpp_sum<0xB1>(a1);
        float t1 = dpp_sum<0xB1>(a2), u1 = dpp_sum<0xB1>(a3);
        float t2 = dpp_sum<0xB1>(a4), u2 = dpp_sum<0xB1>(a5);
        float t3 = dpp_sum<0xB1>(a6), u3 = dpp_sum<0xB1>(a7);
        float q0 = b0 ? u0 : t0;
        float q1 = b0 ? u1 : t1;
        float q2 = b0 ? u2 : t2;
        float q3 = b0 ? u3 : t3;
        float r0a = dpp_sum<0x4E>(q0), r0b = dpp_sum<0x4E>(q1);
        float r1a = dpp_sum<0x4E>(q2), r1b = dpp_sum<0x4E>(q3);
        float r0 = b1 ? r0b : r0a;
        float r1 = b1 ? r1b : r1a;
        float f0 = swz4_sum(r0), f1 = swz4_sum(r1);
        float accv = (b2 ? f1 : f0) + bsum;
        float e  = __expf(2.0f * accv);
        float th = 1.0f - 2.0f * __builtin_amdgcn_rcpf(e + 1.0f);
        sm.hbuf[1 - par][t >> 6][t & 63] = (_Float16)th;
        hlast = th;
        xa = xa_n; xb = xb_n;
        __syncthreads();
    }
    out[(size_t)b * HID + t] = hlast;
    out[(size_t)BATCH * HID + (size_t)b * HID + t] = hlast;
}

extern "C" void kernel_launch(void* const* d_in, const int* in_sizes, int n_in,
                              void* d_out, int out_size, void* d_ws, size_t ws_size,
                              hipStream_t stream) {
    (void)in_sizes; (void)n_in; (void)out_size;
    const float* x    = (const float*)d_in[0];
    const float* h0   = (const float*)d_in[1];
    const float* W_ih = (const float*)d_in[2];
    const float* W_hh = (const float*)d_in[3];
    const float* b_ih = (const float*)d_in[4];
    const float* b_hh = (const float*)d_in[5];
    float* out = (float*)d_out;

    if (ws_size >= WS_NEED) {
        f16*      xp    = (f16*)d_ws;
        u64*      exch  = (u64*)((char*)d_ws + XP_BYTES);
        uint32_t* flags = (uint32_t*)((char*)d_ws + XP_BYTES + EXCH_BYTES);
        hipMemsetAsync(flags, 0, FLAG_BYTES, stream);
        hipLaunchKernelGGL(xp_gemm_kernel, dim3(16, 16), dim3(256), 0, stream,
                           x, W_ih, b_ih, b_hh, xp);
        hipLaunchKernelGGL(rnn_pair_kernel, dim3(32), dim3(512), 0, stream,
                           h0, W_hh, xp, exch, flags, out);
    } else {
        hipLaunchKernelGGL(rnn_ksplit_kernel, dim3(BATCH), dim3(512), 0, stream,
                           x, h0, W_ih, W_hh, b_ih, b_hh, out);
    }
}

// Round 9
// 1025.940 us; speedup vs baseline: 3.0888x; 2.5988x over previous
//
#include <hip/hip_runtime.h>
#include <stdint.h>

#define BATCH 256
#define SEQ   512
#define INDIM 64
#define HID   512

typedef _Float16 f16;
typedef _Float16 f16x2 __attribute__((ext_vector_type(2)));
typedef _Float16 f16x8 __attribute__((ext_vector_type(8)));
typedef float    f32x4 __attribute__((ext_vector_type(4)));

#define XP_BYTES  134217728ULL   // 16 bb * 512 s * 32 tau * 64 lanes * 8 B
#define WS_NEED   XP_BYTES

// Row permutation: D-layout -> next-step B-frag conversion is lane-local.
// wv in [0,8), rho in [0,4), m in [0,16).  (validated rounds 5-8)
__device__ __forceinline__ int row_of8(int wv, int rho, int m) {
    return wv*64 + (rho>>1)*32 + (m>>2)*8 + (rho&1)*4 + (m&3);
}
__device__ __forceinline__ f16x2 pkrtz(float a, float b) {
    return __builtin_bit_cast(f16x2, __builtin_amdgcn_cvt_pkrtz(a, b));
}
union FU { f16x8 v; f16x2 h2[4]; uint32_t u[4]; };
__device__ __forceinline__ f16x8 pack8(float4 a, float4 b) {
    FU r;
    r.h2[0] = pkrtz(a.x, a.y); r.h2[1] = pkrtz(a.z, a.w);
    r.h2[2] = pkrtz(b.x, b.y); r.h2[3] = pkrtz(b.z, b.w);
    return r.v;
}
__device__ __forceinline__ float fast_tanh(float x) {
    float e = __expf(2.0f * x);
    return 1.0f - 2.0f * __builtin_amdgcn_rcpf(e + 1.0f);
}
__device__ __forceinline__ f32x4 mfma16(f16x8 a, f16x8 b, f32x4 c) {
    return __builtin_amdgcn_mfma_f32_16x16x32_f16(a, b, c, 0, 0, 0);
}

// ---- xp = x @ W_ih^T + b_ih + b_hh, stored f16 in D-frag layout (validated) ----
__global__ __launch_bounds__(256)
void xp_gemm_kernel(const float* __restrict__ x, const float* __restrict__ W_ih,
                    const float* __restrict__ b_ih, const float* __restrict__ b_hh,
                    f16* __restrict__ xp)
{
    const int t = threadIdx.x, w = t >> 6, l = t & 63, g = l >> 4, c = l & 15;
    const int bb = blockIdx.x;          // batch block 0..15
    const int sc = blockIdx.y;          // s chunk 0..15

    f16x8 wf[8][2];
    float bias[8][4];
    #pragma unroll
    for (int j = 0; j < 8; ++j) {
        const int tau = w * 8 + j, wv = tau >> 2, rho = tau & 3;
        const float* pr = W_ih + (size_t)row_of8(wv, rho, c) * INDIM;
        #pragma unroll
        for (int kx = 0; kx < 2; ++kx) {
            const float* p4 = pr + kx * 32 + g * 8;
            wf[j][kx] = pack8(((const float4*)p4)[0], ((const float4*)p4)[1]);
        }
        #pragma unroll
        for (int r = 0; r < 4; ++r) {
            int row = row_of8(wv, rho, 4 * g + r);
            bias[j][r] = b_ih[row] + b_hh[row];
        }
    }

    const float* xb = x + (size_t)(bb * 16 + c) * SEQ * INDIM;
    #pragma unroll 1
    for (int si = 0; si < 32; ++si) {
        const int s = sc * 32 + si;
        const float* xs = xb + (size_t)s * INDIM;
        f16x8 bx[2];
        #pragma unroll
        for (int kx = 0; kx < 2; ++kx) {
            const float* p4 = xs + kx * 32 + g * 8;
            bx[kx] = pack8(((const float4*)p4)[0], ((const float4*)p4)[1]);
        }
        #pragma unroll
        for (int j = 0; j < 8; ++j) {
            f32x4 acc; acc[0] = bias[j][0]; acc[1] = bias[j][1];
            acc[2] = bias[j][2]; acc[3] = bias[j][3];
            acc = mfma16(wf[j][0], bx[0], acc);
            acc = mfma16(wf[j][1], bx[1], acc);
            f16x2 lo = pkrtz(acc[0], acc[1]), hi = pkrtz(acc[2], acc[3]);
            uint2 st;
            st.x = __builtin_bit_cast(uint32_t, lo);
            st.y = __builtin_bit_cast(uint32_t, hi);
            size_t idx = (((size_t)bb * SEQ + s) * 32 + w * 8 + j) * 64 + l;
            *(uint2*)(xp + idx * 4) = st;
        }
    }
}

// ---- fully-resident recurrent kernel: 16 blocks x 512 thr (8 waves, 2/SIMD) ----
// W_hh: 12 kappa in regs (192 packed, AGPR-ok) + 4 kappa in LDS (128 KB).
// B-frags: own 2 kappa in regs; 14 from 32 KB h double-buffer. LDS = 160 KB exact.
__global__ __launch_bounds__(512, 2)
void rnn_res_kernel(const float* __restrict__ h0, const float* __restrict__ W_hh,
                    const f16* __restrict__ xp, float* __restrict__ out)
{
    __shared__ f16x8 s_wa[4 * 32 * 64];    // 128 KB: A-frags, per-wave kappa set
    __shared__ f16x8 s_hbuf[2][16 * 64];   // 32 KB: h frag double buffer
    const int t = threadIdx.x, wv = t >> 6, l = t & 63, g = l >> 4, c = l & 15;
    const int bb = blockIdx.x;

    // W_hh kappa (2wv+j)&15, j=0..11 into registers (per-wave rotated -> indices compile-time)
    f16x8 wreg[12][4];
    #pragma unroll
    for (int j = 0; j < 12; ++j) {
        const int kap = (2 * wv + j) & 15;
        #pragma unroll
        for (int rho = 0; rho < 4; ++rho) {
            const float* p4 = W_hh + (size_t)row_of8(wv, rho, c) * HID + kap * 32 + g * 8;
            wreg[j][rho] = pack8(((const float4*)p4)[0], ((const float4*)p4)[1]);
        }
    }
    // W_hh kappa (2wv+12+j)&15, j=0..3 into LDS (this wave's own tiles only)
    #pragma unroll
    for (int j = 0; j < 4; ++j) {
        const int kap = (2 * wv + 12 + j) & 15;
        #pragma unroll
        for (int rho = 0; rho < 4; ++rho) {
            const float* p4 = W_hh + (size_t)row_of8(wv, rho, c) * HID + kap * 32 + g * 8;
            s_wa[(j * 32 + wv * 4 + rho) * 64 + l] =
                pack8(((const float4*)p4)[0], ((const float4*)p4)[1]);
        }
    }

    // h0: own B-frags (kappa 2wv, 2wv+1) in regs + all frags to LDS
    f16x8 ownb[2];
    #pragma unroll
    for (int P = 0; P < 2; ++P) {
        const int kap = 2 * wv + P;
        const float* p4 = h0 + (size_t)(bb * 16 + c) * HID + kap * 32 + g * 8;
        ownb[P] = pack8(((const float4*)p4)[0], ((const float4*)p4)[1]);
        s_hbuf[0][kap * 64 + l] = ownb[P];
    }

    // xp running pointer; prefetch step 0
    const f16* xq = xp + ((((size_t)bb * SEQ) * 32 + wv * 4) * 64 + l) * 4;
    uint2 xn[4];
    #pragma unroll
    for (int rho = 0; rho < 4; ++rho) xn[rho] = *(const uint2*)(xq + rho * 256);

#define PH_OWN(P) { f16x8 bf = ownb[P]; \
        acc[0] = mfma16(wreg[P][0], bf, acc[0]); \
        acc[1] = mfma16(wreg[P][1], bf, acc[1]); \
        acc[2] = mfma16(wreg[P][2], bf, acc[2]); \
        acc[3] = mfma16(wreg[P][3], bf, acc[3]); }
#define PH_REG(J) { f16x8 bf = hb[(((2 * wv + (J)) & 15)) * 64 + l]; \
        acc[0] = mfma16(wreg[J][0], bf, acc[0]); \
        acc[1] = mfma16(wreg[J][1], bf, acc[1]); \
        acc[2] = mfma16(wreg[J][2], bf, acc[2]); \
        acc[3] = mfma16(wreg[J][3], bf, acc[3]); }
#define PH_LDS(J) { f16x8 bf = hb[(((2 * wv + 12 + (J)) & 15)) * 64 + l]; \
        acc[0] = mfma16(s_wa[((J) * 32 + wv * 4 + 0) * 64 + l], bf, acc[0]); \
        acc[1] = mfma16(s_wa[((J) * 32 + wv * 4 + 1) * 64 + l], bf, acc[1]); \
        acc[2] = mfma16(s_wa[((J) * 32 + wv * 4 + 2) * 64 + l], bf, acc[2]); \
        acc[3] = mfma16(s_wa[((J) * 32 + wv * 4 + 3) * 64 + l], bf, acc[3]); }

    __syncthreads();

    int p = 0;
    #pragma unroll 1
    for (int tt = 0; tt < SEQ; ++tt) {
        // acc init from xp (f16 -> f32)
        f32x4 acc[4];
        #pragma unroll
        for (int rho = 0; rho < 4; ++rho) {
            f16x2 lo = __builtin_bit_cast(f16x2, xn[rho].x);
            f16x2 hi = __builtin_bit_cast(f16x2, xn[rho].y);
            f32x4 a; a[0] = (float)lo[0]; a[1] = (float)lo[1];
            a[2] = (float)hi[0]; a[3] = (float)hi[1];
            acc[rho] = a;
        }
        // xp prefetch for next step (in flight across the whole MFMA phase)
        {
            const f16* xr = (tt + 1 < SEQ) ? xq + 8192 : xq;
            #pragma unroll
            for (int rho = 0; rho < 4; ++rho)
                xn[rho] = *(const uint2*)(xr + rho * 256);
            xq = xr;
        }

        const f16x8* hb = &s_hbuf[p][0];

        // own-kappa first (B from regs), then reg-A, then LDS-A phases
        PH_OWN(0) PH_OWN(1)
        PH_REG(2) PH_REG(3) PH_REG(4)  PH_REG(5)
        PH_REG(6) PH_REG(7) PH_REG(8)  PH_REG(9)
        PH_REG(10) PH_REG(11)
        PH_LDS(0) PH_LDS(1) PH_LDS(2)  PH_LDS(3)

        // tanh -> pack (lane-local) -> own B-frags + LDS publish
        f16x8* hw = &s_hbuf[1 - p][0];
        #pragma unroll
        for (int P = 0; P < 2; ++P) {
            float t0 = fast_tanh(acc[2*P][0]),   t1 = fast_tanh(acc[2*P][1]);
            float t2 = fast_tanh(acc[2*P][2]),   t3 = fast_tanh(acc[2*P][3]);
            float t4 = fast_tanh(acc[2*P+1][0]), t5 = fast_tanh(acc[2*P+1][1]);
            float t6 = fast_tanh(acc[2*P+1][2]), t7 = fast_tanh(acc[2*P+1][3]);
            FU fu;
            fu.h2[0] = pkrtz(t0, t1); fu.h2[1] = pkrtz(t2, t3);
            fu.h2[2] = pkrtz(t4, t5); fu.h2[3] = pkrtz(t6, t7);
            ownb[P] = fu.v;
            hw[(2 * wv + P) * 64 + l] = fu.v;
            if (tt == SEQ - 1) {
                float* ob = out + (size_t)(bb * 16 + c) * HID;
                float* o2 = ob + (size_t)BATCH * HID;
                int ra = row_of8(wv, 2 * P, 4 * g);      // rows ra..ra+3 = t0..t3
                int rb = ra + 4;                          // rows rb..rb+3 = t4..t7
                ob[ra + 0] = t0; ob[ra + 1] = t1; ob[ra + 2] = t2; ob[ra + 3] = t3;
                ob[rb + 0] = t4; ob[rb + 1] = t5; ob[rb + 2] = t6; ob[rb + 3] = t7;
                o2[ra + 0] = t0; o2[ra + 1] = t1; o2[ra + 2] = t2; o2[ra + 3] = t3;
                o2[rb + 0] = t4; o2[rb + 1] = t5; o2[rb + 2] = t6; o2[rb + 3] = t7;
            }
        }

        // step barrier: drain LDS ops; (only xp loads outstanding on vmcnt)
        asm volatile("s_waitcnt lgkmcnt(0)" ::: "memory");
        __builtin_amdgcn_s_barrier();
        asm volatile("" ::: "memory");
        p ^= 1;
    }
#undef PH_OWN
#undef PH_REG
#undef PH_LDS
}

// =================== fallback (round-2 kernel, proven 962 us) ===============
typedef _Float16 half2_t __attribute__((ext_vector_type(2)));
__device__ __forceinline__ float dot2f(uint32_t w, uint32_t h, float acc) {
    return __builtin_amdgcn_fdot2(__builtin_bit_cast(half2_t, w),
                                  __builtin_bit_cast(half2_t, h), acc, false);
}
__device__ __forceinline__ uint32_t pack2(float a, float b) {
    half2_t h; h[0] = (_Float16)a; h[1] = (_Float16)b;
    return __builtin_bit_cast(uint32_t, h);
}
template<int CTRL>
__device__ __forceinline__ float dpp_sum(float x) {
    int xi = __builtin_bit_cast(int, x);
    int yi = __builtin_amdgcn_mov_dpp(xi, CTRL, 0xF, 0xF, true);
    return x + __builtin_bit_cast(float, yi);
}
__device__ __forceinline__ float swz4_sum(float x) {
    int xi = __builtin_bit_cast(int, x);
    int yi = __builtin_amdgcn_ds_swizzle(xi, 0x101F);
    return x + __builtin_bit_cast(float, yi);
}
struct SmemFB {
    uint4     wl[16][512];
    _Float16  hbuf[2][8][72];
};
#define FB_DOT4(accv, wrow, hc) \
    accv = dot2f((wrow)[0], hc.x, accv); accv = dot2f((wrow)[1], hc.y, accv); \
    accv = dot2f((wrow)[2], hc.z, accv); accv = dot2f((wrow)[3], hc.w, accv);

__global__ __launch_bounds__(512, 2)
void rnn_ksplit_kernel(const float* __restrict__ x, const float* __restrict__ h0,
                       const float* __restrict__ W_ih, const float* __restrict__ W_hh,
                       const float* __restrict__ b_ih, const float* __restrict__ b_hh,
                       float* __restrict__ out)
{
    __shared__ SmemFB sm;
    const int t = threadIdx.x;
    const int b = blockIdx.x;
    const int s = t & 7;
    const int rbase = t & ~7;

    uint32_t wreg[6][32];
    #pragma unroll
    for (int j = 0; j < 6; ++j) {
        const float* wr = W_hh + (size_t)(rbase + j) * HID + s * 64;
        #pragma unroll
        for (int q = 0; q < 16; ++q) {
            float4 v4 = ((const float4*)wr)[q];
            wreg[j][2*q]   = pack2(v4.x, v4.y);
            wreg[j][2*q+1] = pack2(v4.z, v4.w);
        }
    }
    #pragma unroll
    for (int v = 0; v < 2; ++v) {
        const float* wr = W_hh + (size_t)(rbase + 6 + v) * HID + s * 64;
        #pragma unroll
        for (int cc = 0; cc < 8; ++cc) {
            float4 aa = ((const float4*)wr)[2*cc];
            float4 bb2 = ((const float4*)wr)[2*cc+1];
            uint4 wv2;
            wv2.x = pack2(aa.x, aa.y); wv2.y = pack2(aa.z, aa.w);
            wv2.z = pack2(bb2.x, bb2.y); wv2.w = pack2(bb2.z, bb2.w);
            sm.wl[v*8 + cc][t] = wv2;
        }
    }
    uint32_t wih[8][4];
    #pragma unroll
    for (int j = 0; j < 8; ++j) {
        const float* wr = W_ih + (size_t)(rbase + j) * INDIM + s * 8;
        float4 aa = ((const float4*)wr)[0];
        float4 bb2 = ((const float4*)wr)[1];
        wih[j][0] = pack2(aa.x, aa.y); wih[j][1] = pack2(aa.z, aa.w);
        wih[j][2] = pack2(bb2.x, bb2.y); wih[j][3] = pack2(bb2.z, bb2.w);
    }
    const float bsum = b_ih[t] + b_hh[t];
    sm.hbuf[0][t >> 6][t & 63] = (_Float16)h0[(size_t)b * HID + t];
    const float* xbase = x + (size_t)b * SEQ * INDIM + s * 8;
    float4 xa = ((const float4*)xbase)[0];
    float4 xb = ((const float4*)xbase)[1];
    const bool b0 = (s & 1) != 0, b1 = (s & 2) != 0, b2 = (s & 4) != 0;
    __syncthreads();

    float hlast = 0.f;
    #pragma unroll 1
    for (int tt = 0; tt < SEQ; ++tt) {
        const int tn = (tt + 1 < SEQ) ? tt + 1 : tt;
        const float* xpf = xbase + (size_t)tn * INDIM;
        float4 xa_n = ((const float4*)xpf)[0];
        float4 xb_n = ((const float4*)xpf)[1];
        const int par = tt & 1;
        float a0=0,a1=0,a2=0,a3=0,a4=0,a5=0,a6=0,a7=0;
        const uint4* hp = (const uint4*)&sm.hbuf[par][s][0];
        #pragma unroll
        for (int cc = 0; cc < 8; ++cc) {
            uint4 hc = hp[cc];
            uint4 w6 = sm.wl[cc][t];
            uint4 w7 = sm.wl[8 + cc][t];
            FB_DOT4(a0, &wreg[0][4*cc], hc);
            FB_DOT4(a1, &wreg[1][4*cc], hc);
            FB_DOT4(a2, &wreg[2][4*cc], hc);
            FB_DOT4(a3, &wreg[3][4*cc], hc);
            FB_DOT4(a4, &wreg[4][4*cc], hc);
            FB_DOT4(a5, &wreg[5][4*cc], hc);
            a6 = dot2f(w6.x, hc.x, a6); a6 = dot2f(w6.y, hc.y, a6);
            a6 = dot2f(w6.z, hc.z, a6); a6 = dot2f(w6.w, hc.w, a6);
            a7 = dot2f(w7.x, hc.x, a7); a7 = dot2f(w7.y, hc.y, a7);
            a7 = dot2f(w7.z, hc.z, a7); a7 = dot2f(w7.w, hc.w, a7);
        }
        {
            uint32_t xp0 = pack2(xa.x, xa.y), xp1 = pack2(xa.z, xa.w);
            uint32_t xp2 = pack2(xb.x, xb.y), xp3 = pack2(xb.z, xb.w);
            uint4 xc; xc.x = xp0; xc.y = xp1; xc.z = xp2; xc.w = xp3;
            FB_DOT4(a0, wih[0], xc); FB_DOT4(a1, wih[1], xc);
            FB_DOT4(a2, wih[2], xc); FB_DOT4(a3, wih[3], xc);
            FB_DOT4(a4, wih[4], xc); FB_DOT4(a5, wih[5], xc);
            FB_DOT4(a6, wih[6], xc); FB_DOT4(a7, wih[7], xc);
        }
        float t0 = dpp_sum<0xB1>(a0), u0 = dpp_sum<0xB1>(a1);
        float t1 = dpp_sum<0xB1>(a2), u1 = dpp_sum<0xB1>(a3);
        float t2 = dpp_sum<0xB1>(a4), u2 = dpp_sum<0xB1>(a5);
        float t3 = dpp_sum<0xB1>(a6), u3 = dpp_sum<0xB1>(a7);
        float q0 = b0 ? u0 : t0;
        float q1 = b0 ? u1 : t1;
        float q2 = b0 ? u2 : t2;
        float q3 = b0 ? u3 : t3;
        float r0a = dpp_sum<0x4E>(q0), r0b = dpp_sum<0x4E>(q1);
        float r1a = dpp_sum<0x4E>(q2), r1b = dpp_sum<0x4E>(q3);
        float r0 = b1 ? r0b : r0a;
        float r1 = b1 ? r1b : r1a;
        float f0 = swz4_sum(r0), f1 = swz4_sum(r1);
        float accv = (b2 ? f1 : f0) + bsum;
        float e  = __expf(2.0f * accv);
        float th = 1.0f - 2.0f * __builtin_amdgcn_rcpf(e + 1.0f);
        sm.hbuf[1 - par][t >> 6][t & 63] = (_Float16)th;
        hlast = th;
        xa = xa_n; xb = xb_n;
        __syncthreads();
    }
    out[(size_t)b * HID + t] = hlast;
    out[(size_t)BATCH * HID + (size_t)b * HID + t] = hlast;
}

extern "C" void kernel_launch(void* const* d_in, const int* in_sizes, int n_in,
                              void* d_out, int out_size, void* d_ws, size_t ws_size,
                              hipStream_t stream) {
    (void)in_sizes; (void)n_in; (void)out_size;
    const float* x    = (const float*)d_in[0];
    const float* h0   = (const float*)d_in[1];
    const float* W_ih = (const float*)d_in[2];
    const float* W_hh = (const float*)d_in[3];
    const float* b_ih = (const float*)d_in[4];
    const float* b_hh = (const float*)d_in[5];
    float* out = (float*)d_out;

    if (ws_size >= WS_NEED) {
        f16* xp = (f16*)d_ws;
        hipLaunchKernelGGL(xp_gemm_kernel, dim3(16, 16), dim3(256), 0, stream,
                           x, W_ih, b_ih, b_hh, xp);
        hipLaunchKernelGGL(rnn_res_kernel, dim3(16), dim3(512), 0, stream,
                           h0, W_hh, xp, out);
    } else {
        hipLaunchKernelGGL(rnn_ksplit_kernel, dim3(BATCH), dim3(512), 0, stream,
                           x, h0, W_ih, W_hh, b_ih, b_hh, out);
    }
}